// Round 11
// baseline (846.760 us; speedup 1.0000x reference)
//
#include <hip/hip_runtime.h>
#include <math.h>

// MAM dense: C[m,n] = max_k(A[m,k]*W[n,k]) + min_k(A[m,k]*W[n,k]) + bias[n]
// A: [M,K] fp32, W: [N,K] fp32 (torch layout), C: [M,N]
//
// R11 = R10 (8x8 micro, in-block split-K, barrier-free main loop) +
//  (a) LDS union: combine buffers overlap staging strips -> 34.8 KB (was 66)
//      -> 4 blocks/CU allowed by LDS; one extra barrier before combine.
//  (b) v_pk_mul_f32 with op_sel broadcast: 1 pk_mul = 2 products, A-halves
//      broadcast straight from b128 read pairs (no packing movs).
//      192 VALU inst per k-pair (was 256) -> 41 us VALU floor.
//  (c) no stage-prefetch ring (saves ~24 VGPR); launch_bounds(256,3).

#define TS 64
#define BK 16
#define LDSP 68
#define STRIPF (BK * LDSP)   // 1088 floats per strip

typedef float f32x2 __attribute__((ext_vector_type(2)));
typedef float f32x4 __attribute__((ext_vector_type(4)));

// (a.lo*b.lo, a.lo*b.hi) -- broadcast low half of A-pair
static __device__ __forceinline__ f32x2 pkmul_blo(f32x2 a, f32x2 b) {
    f32x2 d;
    asm("v_pk_mul_f32 %0, %1, %2 op_sel:[0,0] op_sel_hi:[0,1]"
        : "=v"(d) : "v"(a), "v"(b));
    return d;
}
// (a.hi*b.lo, a.hi*b.hi) -- broadcast high half of A-pair
static __device__ __forceinline__ f32x2 pkmul_bhi(f32x2 a, f32x2 b) {
    f32x2 d;
    asm("v_pk_mul_f32 %0, %1, %2 op_sel:[1,0] op_sel_hi:[1,1]"
        : "=v"(d) : "v"(a), "v"(b));
    return d;
}
__device__ __forceinline__ void mam_upd(float& mx, float& mn, float p0, float p1) {
    float nmx, nmn;
    asm("v_max3_f32 %0, %1, %2, %3" : "=v"(nmx) : "v"(p0), "v"(p1), "v"(mx));
    asm("v_min3_f32 %0, %1, %2, %3" : "=v"(nmn) : "v"(p0), "v"(p1), "v"(mn));
    mx = nmx;
    mn = nmn;
}

__global__ __launch_bounds__(256, 3) void mam_sk(
    const float* __restrict__ A, const float* __restrict__ W,
    const float* __restrict__ bias, float* __restrict__ C,
    int M, int N, int K)
{
    // union: [0 .. 4*STRIPF) = sA strips, [4*STRIPF .. 8*STRIPF) = sW strips;
    // after main loop (barrier) the same memory holds cmx[4096] + cmn[4096].
    __shared__ __align__(16) float smem[8 * STRIPF];   // 34816 B
    float* cmx = smem;
    float* cmn = smem + TS * TS;

    const int t    = threadIdx.x;
    const int w    = t >> 6;        // wave id == k-group
    const int lane = t & 63;
    const int ty   = lane >> 3;     // m micro thread (8 rows)
    const int tx   = lane & 7;      // n micro thread (8 cols)
    const int m0   = blockIdx.y * TS;
    const int n0   = blockIdx.x * TS;
    const int kc   = K >> 2;        // 256 k per wave
    const int kb0  = w * kc;

    const int sr = lane >> 2;       // staging row 0..15
    const int sc = lane & 3;        // staging k-quad 0..3

    float* sAw = smem + (size_t)w * STRIPF;               // this wave's A strip
    float* sWw = smem + (size_t)(4 + w) * STRIPF;         // this wave's W strip

    const float* Ap = A + (size_t)(m0 + sr) * K + kb0 + sc * 4;
    const float* Wp = W + (size_t)(n0 + sr) * K + kb0 + sc * 4;

    float mx[8][8], mn[8][8];
#pragma unroll
    for (int i = 0; i < 8; ++i)
#pragma unroll
        for (int j = 0; j < 8; ++j) {
            mx[i][j] = -INFINITY;
            mn[i][j] =  INFINITY;
        }

    const int nStages = kc / BK;    // 16
    for (int s = 0; s < nStages; ++s) {
        // ---- load + scatter this stage (per-q to limit live registers) ----
#pragma unroll
        for (int q = 0; q < 4; ++q) {
            float4 la = *(const float4*)(Ap + (size_t)q * 16 * K);
            float4 lw = *(const float4*)(Wp + (size_t)q * 16 * K);
            const int mI = sr + q * 16;
            sAw[(sc * 4 + 0) * LDSP + mI] = la.x;
            sAw[(sc * 4 + 1) * LDSP + mI] = la.y;
            sAw[(sc * 4 + 2) * LDSP + mI] = la.z;
            sAw[(sc * 4 + 3) * LDSP + mI] = la.w;
            sWw[(sc * 4 + 0) * LDSP + mI] = lw.x;
            sWw[(sc * 4 + 1) * LDSP + mI] = lw.y;
            sWw[(sc * 4 + 2) * LDSP + mI] = lw.z;
            sWw[(sc * 4 + 3) * LDSP + mI] = lw.w;
        }
        Ap += BK;
        Wp += BK;

        // ---- compute 8 k-pairs (no barrier: strip is wave-private,
        //      same-wave DS ops are ordered) ----
#pragma unroll
        for (int k = 0; k < BK; k += 2) {
            f32x4 A0lo = *(const f32x4*)&sAw[(k    ) * LDSP + ty * 8];
            f32x4 A0hi = *(const f32x4*)&sAw[(k    ) * LDSP + ty * 8 + 4];
            f32x4 A1lo = *(const f32x4*)&sAw[(k + 1) * LDSP + ty * 8];
            f32x4 A1hi = *(const f32x4*)&sAw[(k + 1) * LDSP + ty * 8 + 4];
            f32x4 W0lo = *(const f32x4*)&sWw[(k    ) * LDSP + tx * 8];
            f32x4 W0hi = *(const f32x4*)&sWw[(k    ) * LDSP + tx * 8 + 4];
            f32x4 W1lo = *(const f32x4*)&sWw[(k + 1) * LDSP + tx * 8];
            f32x4 W1hi = *(const f32x4*)&sWw[(k + 1) * LDSP + tx * 8 + 4];

            f32x2 a0p[4] = {A0lo.lo, A0lo.hi, A0hi.lo, A0hi.hi};
            f32x2 a1p[4] = {A1lo.lo, A1lo.hi, A1hi.lo, A1hi.hi};
            f32x2 b0p[4] = {W0lo.lo, W0lo.hi, W0hi.lo, W0hi.hi};
            f32x2 b1p[4] = {W1lo.lo, W1lo.hi, W1hi.lo, W1hi.hi};

#pragma unroll
            for (int ip = 0; ip < 4; ++ip) {
#pragma unroll
                for (int jp = 0; jp < 4; ++jp) {
                    f32x2 P0 = pkmul_blo(a0p[ip], b0p[jp]);  // m=2ip,   k
                    f32x2 Q0 = pkmul_blo(a1p[ip], b1p[jp]);  // m=2ip,   k+1
                    mam_upd(mx[2 * ip][2 * jp],     mn[2 * ip][2 * jp],     P0.x, Q0.x);
                    mam_upd(mx[2 * ip][2 * jp + 1], mn[2 * ip][2 * jp + 1], P0.y, Q0.y);
                    f32x2 P1 = pkmul_bhi(a0p[ip], b0p[jp]);  // m=2ip+1, k
                    f32x2 Q1 = pkmul_bhi(a1p[ip], b1p[jp]);  // m=2ip+1, k+1
                    mam_upd(mx[2 * ip + 1][2 * jp],     mn[2 * ip + 1][2 * jp],     P1.x, Q1.x);
                    mam_upd(mx[2 * ip + 1][2 * jp + 1], mn[2 * ip + 1][2 * jp + 1], P1.y, Q1.y);
                }
            }
        }
    }

    // strips are now dead; cmx/cmn overlap them -> must drain all waves first
    __syncthreads();

    // ---- cross-wave combine: sequential merge rounds through LDS ----
    for (int rnd = 0; rnd < 4; ++rnd) {
        if (w == rnd) {
#pragma unroll
            for (int i = 0; i < 8; ++i)
#pragma unroll
                for (int j = 0; j < 8; ++j) {
                    const int idx = (ty * 8 + i) * TS + tx * 8 + j;
                    if (rnd == 0) {
                        cmx[idx] = mx[i][j];
                        cmn[idx] = mn[i][j];
                    } else {
                        cmx[idx] = fmaxf(cmx[idx], mx[i][j]);
                        cmn[idx] = fminf(cmn[idx], mn[i][j]);
                    }
                }
        }
        __syncthreads();
    }

    // ---- bias + store: wave w writes micro-rows i = {2w, 2w+1} ----
    float4 blo = *(const float4*)(bias + n0 + tx * 8);
    float4 bhi = *(const float4*)(bias + n0 + tx * 8 + 4);
#pragma unroll
    for (int i2 = 0; i2 < 2; ++i2) {
        const int i   = w * 2 + i2;
        const int row = ty * 8 + i;
        const int idx = row * TS + tx * 8;
        float4 o0, o1;
        o0.x = cmx[idx + 0] + cmn[idx + 0] + blo.x;
        o0.y = cmx[idx + 1] + cmn[idx + 1] + blo.y;
        o0.z = cmx[idx + 2] + cmn[idx + 2] + blo.z;
        o0.w = cmx[idx + 3] + cmn[idx + 3] + blo.w;
        o1.x = cmx[idx + 4] + cmn[idx + 4] + bhi.x;
        o1.y = cmx[idx + 5] + cmn[idx + 5] + bhi.y;
        o1.z = cmx[idx + 6] + cmn[idx + 6] + bhi.z;
        o1.w = cmx[idx + 7] + cmn[idx + 7] + bhi.w;
        float4* p = (float4*)(C + (size_t)(m0 + row) * N + n0 + tx * 8);
        p[0] = o0;
        p[1] = o1;
    }
}

// ---- fallback (proven R2 kernel) for shapes the fast path can't take ----
#define BM 64
#define BN 64
#define FBK 32
#define LDSW 68

__device__ __forceinline__ void mam_upd_fb(float& mx, float& mn, float p0, float p1) {
    float nmx, nmn;
    asm("v_max3_f32 %0, %1, %2, %3" : "=v"(nmx) : "v"(p0), "v"(p1), "v"(mx));
    asm("v_min3_f32 %0, %1, %2, %3" : "=v"(nmn) : "v"(p0), "v"(p1), "v"(mn));
    mx = nmx;
    mn = nmn;
}

__global__ __launch_bounds__(256) void mam_fallback(
    const float* __restrict__ A, const float* __restrict__ W,
    const float* __restrict__ bias, float* __restrict__ C,
    int M, int N, int K)
{
    __shared__ float Asf[FBK][LDSW];
    __shared__ float Wsf[FBK][LDSW];

    const int t  = threadIdx.x;
    const int tx = t & 15;
    const int ty = t >> 4;
    const int m0 = blockIdx.y * BM;
    const int n0 = blockIdx.x * BN;
    const int r  = t >> 3;
    const int kq = t & 7;

    const float* Aptr = A + (size_t)(m0 + r) * K + kq * 4;
    const float* Wptr = W + (size_t)(n0 + r) * K + kq * 4;

    float vmax[4][4], vmin[4][4];
#pragma unroll
    for (int i = 0; i < 4; ++i)
#pragma unroll
        for (int j = 0; j < 4; ++j) {
            vmax[i][j] = -INFINITY;
            vmin[i][j] =  INFINITY;
        }

    for (int k0 = 0; k0 < K; k0 += FBK) {
        float4 a0 = *(const float4*)(Aptr);
        float4 a1 = *(const float4*)(Aptr + (size_t)32 * K);
        float4 w0 = *(const float4*)(Wptr);
        float4 w1 = *(const float4*)(Wptr + (size_t)32 * K);
        Aptr += FBK;
        Wptr += FBK;

        const int kk = kq * 4;
        Asf[kk + 0][r]      = a0.x;
        Asf[kk + 1][r]      = a0.y;
        Asf[kk + 2][r]      = a0.z;
        Asf[kk + 3][r]      = a0.w;
        Asf[kk + 0][r + 32] = a1.x;
        Asf[kk + 1][r + 32] = a1.y;
        Asf[kk + 2][r + 32] = a1.z;
        Asf[kk + 3][r + 32] = a1.w;

        Wsf[kk + 0][r]      = w0.x;
        Wsf[kk + 1][r]      = w0.y;
        Wsf[kk + 2][r]      = w0.z;
        Wsf[kk + 3][r]      = w0.w;
        Wsf[kk + 0][r + 32] = w1.x;
        Wsf[kk + 1][r + 32] = w1.y;
        Wsf[kk + 2][r + 32] = w1.z;
        Wsf[kk + 3][r + 32] = w1.w;

        __syncthreads();

#pragma unroll
        for (int k = 0; k < FBK; k += 2) {
            float4 ta0 = *(const float4*)&Asf[k    ][ty * 4];
            float4 ta1 = *(const float4*)&Asf[k + 1][ty * 4];
            float4 tb0 = *(const float4*)&Wsf[k    ][tx * 4];
            float4 tb1 = *(const float4*)&Wsf[k + 1][tx * 4];

            float a0v[4] = {ta0.x, ta0.y, ta0.z, ta0.w};
            float a1v[4] = {ta1.x, ta1.y, ta1.z, ta1.w};
            float b0v[4] = {tb0.x, tb0.y, tb0.z, tb0.w};
            float b1v[4] = {tb1.x, tb1.y, tb1.z, tb1.w};

#pragma unroll
            for (int i = 0; i < 4; ++i)
#pragma unroll
                for (int j = 0; j < 4; ++j) {
                    float p0 = a0v[i] * b0v[j];
                    float p1 = a1v[i] * b1v[j];
                    mam_upd_fb(vmax[i][j], vmin[i][j], p0, p1);
                }
        }
        __syncthreads();
    }

    float4 bv = *(const float4*)(bias + n0 + tx * 4);
#pragma unroll
    for (int i = 0; i < 4; ++i) {
        float4 o;
        o.x = vmax[i][0] + vmin[i][0] + bv.x;
        o.y = vmax[i][1] + vmin[i][1] + bv.y;
        o.z = vmax[i][2] + vmin[i][2] + bv.z;
        o.w = vmax[i][3] + vmin[i][3] + bv.w;
        *(float4*)(C + (size_t)(m0 + ty * 4 + i) * N + n0 + tx * 4) = o;
    }
}

extern "C" void kernel_launch(void* const* d_in, const int* in_sizes, int n_in,
                              void* d_out, int out_size, void* d_ws, size_t ws_size,
                              hipStream_t stream) {
    const float* x    = (const float*)d_in[0];
    const float* w    = (const float*)d_in[1];
    const float* bias = (const float*)d_in[2];
    float* out = (float*)d_out;

    const int N = in_sizes[2];
    const int K = in_sizes[1] / N;
    const int M = in_sizes[0] / K;

    const bool fast_ok = (K % (4 * BK) == 0) && (M % TS == 0) && (N % TS == 0);

    if (fast_ok) {
        dim3 grid(N / TS, M / TS);   // (16, 32) = 512 blocks
        mam_sk<<<grid, 256, 0, stream>>>(x, w, bias, out, M, N, K);
    } else {
        dim3 grid(N / BN, M / BM);
        mam_fallback<<<grid, 256, 0, stream>>>(x, w, bias, out, M, N, K);
    }
}

// Round 12
// 153.933 us; speedup vs baseline: 5.5008x; 5.5008x over previous
//
#include <hip/hip_runtime.h>
#include <math.h>

// MAM dense: C[m,n] = max_k(A[m,k]*W[n,k]) + min_k(A[m,k]*W[n,k]) + bias[n]
// A: [M,K] fp32, W: [N,K] fp32 (torch layout), C: [M,N]
//
// R12 = R10's exact inner loop (scalar mul + v_max3/v_min3, 8x8 micro,
// in-block split-K, barrier-free main loop, prefetch ring, VGPR=116, no
// spills) + ONLY the LDS union: combine buffers overlap the dead staging
// strips -> 34.8 KB (was 66 KB) -> 4 blocks/CU instead of 2. R11's pk_mul
// experiment spilled (VGPR pairs + 128 asm accumulators + (256,3) cap ->
// scratch traffic 2 GB); reverted entirely.

#define TS 64
#define BK 16
#define LDSP 68
#define STRIPF (BK * LDSP)   // 1088 floats per strip

__device__ __forceinline__ void mam_upd(float& mx, float& mn, float p0, float p1) {
    float nmx, nmn;
    asm("v_max3_f32 %0, %1, %2, %3" : "=v"(nmx) : "v"(p0), "v"(p1), "v"(mx));
    asm("v_min3_f32 %0, %1, %2, %3" : "=v"(nmn) : "v"(p0), "v"(p1), "v"(mn));
    mx = nmx;
    mn = nmn;
}

__global__ __launch_bounds__(256, 2) void mam_sk(
    const float* __restrict__ A, const float* __restrict__ W,
    const float* __restrict__ bias, float* __restrict__ C,
    int M, int N, int K)
{
    // union: [0..4*STRIPF) sA strips, [4*STRIPF..8*STRIPF) sW strips;
    // after the main loop (barrier) the same memory holds cmx/cmn (64x64 each).
    __shared__ __align__(16) float smem[8 * STRIPF];   // 34816 B
    float* cmx = smem;
    float* cmn = smem + TS * TS;

    const int t    = threadIdx.x;
    const int w    = t >> 6;        // wave id == k-group
    const int lane = t & 63;
    const int ty   = lane >> 3;     // m micro thread (8 rows)
    const int tx   = lane & 7;      // n micro thread (8 cols)
    const int m0   = blockIdx.y * TS;
    const int n0   = blockIdx.x * TS;
    const int kc   = K >> 2;        // 256 k per wave
    const int kb0  = w * kc;

    const int sr = lane >> 2;       // staging row 0..15
    const int sc = lane & 3;        // staging k-quad 0..3

    float* sAw = smem + (size_t)w * STRIPF;          // this wave's A strip
    float* sWw = smem + (size_t)(4 + w) * STRIPF;    // this wave's W strip

    const float* Ap = A + (size_t)(m0 + sr) * K + kb0 + sc * 4;
    const float* Wp = W + (size_t)(n0 + sr) * K + kb0 + sc * 4;

    float mx[8][8], mn[8][8];
#pragma unroll
    for (int i = 0; i < 8; ++i)
#pragma unroll
        for (int j = 0; j < 8; ++j) {
            mx[i][j] = -INFINITY;
            mn[i][j] =  INFINITY;
        }

    float4 ra[4], rw[4];
#pragma unroll
    for (int q = 0; q < 4; ++q) {
        ra[q] = *(const float4*)(Ap + (size_t)q * 16 * K);
        rw[q] = *(const float4*)(Wp + (size_t)q * 16 * K);
    }
    Ap += BK;
    Wp += BK;

    const int nStages = kc / BK;    // 16
    for (int s = 0; s < nStages; ++s) {
        // scatter current stage into this wave's strip (no barrier: strip is
        // wave-private; same-wave DS ops are ordered)
#pragma unroll
        for (int q = 0; q < 4; ++q) {
            const int mI = sr + q * 16;
            sAw[(sc * 4 + 0) * LDSP + mI] = ra[q].x;
            sAw[(sc * 4 + 1) * LDSP + mI] = ra[q].y;
            sAw[(sc * 4 + 2) * LDSP + mI] = ra[q].z;
            sAw[(sc * 4 + 3) * LDSP + mI] = ra[q].w;
            sWw[(sc * 4 + 0) * LDSP + mI] = rw[q].x;
            sWw[(sc * 4 + 1) * LDSP + mI] = rw[q].y;
            sWw[(sc * 4 + 2) * LDSP + mI] = rw[q].z;
            sWw[(sc * 4 + 3) * LDSP + mI] = rw[q].w;
        }
        // prefetch next stage while computing this one
        if (s + 1 < nStages) {
#pragma unroll
            for (int q = 0; q < 4; ++q) {
                ra[q] = *(const float4*)(Ap + (size_t)q * 16 * K);
                rw[q] = *(const float4*)(Wp + (size_t)q * 16 * K);
            }
            Ap += BK;
            Wp += BK;
        }

#pragma unroll
        for (int k = 0; k < BK; k += 2) {
            float4 a00 = *(const float4*)&sAw[(k    ) * LDSP + ty * 8];
            float4 a01 = *(const float4*)&sAw[(k    ) * LDSP + ty * 8 + 4];
            float4 a10 = *(const float4*)&sAw[(k + 1) * LDSP + ty * 8];
            float4 a11 = *(const float4*)&sAw[(k + 1) * LDSP + ty * 8 + 4];
            float4 w00 = *(const float4*)&sWw[(k    ) * LDSP + tx * 8];
            float4 w01 = *(const float4*)&sWw[(k    ) * LDSP + tx * 8 + 4];
            float4 w10 = *(const float4*)&sWw[(k + 1) * LDSP + tx * 8];
            float4 w11 = *(const float4*)&sWw[(k + 1) * LDSP + tx * 8 + 4];

            float a0[8] = {a00.x, a00.y, a00.z, a00.w, a01.x, a01.y, a01.z, a01.w};
            float a1[8] = {a10.x, a10.y, a10.z, a10.w, a11.x, a11.y, a11.z, a11.w};
            float b0[8] = {w00.x, w00.y, w00.z, w00.w, w01.x, w01.y, w01.z, w01.w};
            float b1[8] = {w10.x, w10.y, w10.z, w10.w, w11.x, w11.y, w11.z, w11.w};

#pragma unroll
            for (int i = 0; i < 8; ++i)
#pragma unroll
                for (int j = 0; j < 8; ++j) {
                    float p0 = a0[i] * b0[j];
                    float p1 = a1[i] * b1[j];
                    mam_upd(mx[i][j], mn[i][j], p0, p1);
                }
        }
    }

    // strips now dead; cmx/cmn overlap them -> drain all waves first
    __syncthreads();

    // ---- cross-wave combine: sequential merge rounds through LDS ----
    for (int rnd = 0; rnd < 4; ++rnd) {
        if (w == rnd) {
#pragma unroll
            for (int i = 0; i < 8; ++i)
#pragma unroll
                for (int j = 0; j < 8; ++j) {
                    const int idx = (ty * 8 + i) * TS + tx * 8 + j;
                    if (rnd == 0) {
                        cmx[idx] = mx[i][j];
                        cmn[idx] = mn[i][j];
                    } else {
                        cmx[idx] = fmaxf(cmx[idx], mx[i][j]);
                        cmn[idx] = fminf(cmn[idx], mn[i][j]);
                    }
                }
        }
        __syncthreads();
    }

    // ---- bias + store: wave w writes micro-rows i = {2w, 2w+1} ----
    float4 blo = *(const float4*)(bias + n0 + tx * 8);
    float4 bhi = *(const float4*)(bias + n0 + tx * 8 + 4);
#pragma unroll
    for (int i2 = 0; i2 < 2; ++i2) {
        const int i   = w * 2 + i2;
        const int row = ty * 8 + i;
        const int idx = row * TS + tx * 8;
        float4 o0, o1;
        o0.x = cmx[idx + 0] + cmn[idx + 0] + blo.x;
        o0.y = cmx[idx + 1] + cmn[idx + 1] + blo.y;
        o0.z = cmx[idx + 2] + cmn[idx + 2] + blo.z;
        o0.w = cmx[idx + 3] + cmn[idx + 3] + blo.w;
        o1.x = cmx[idx + 4] + cmn[idx + 4] + bhi.x;
        o1.y = cmx[idx + 5] + cmn[idx + 5] + bhi.y;
        o1.z = cmx[idx + 6] + cmn[idx + 6] + bhi.z;
        o1.w = cmx[idx + 7] + cmn[idx + 7] + bhi.w;
        float4* p = (float4*)(C + (size_t)(m0 + row) * N + n0 + tx * 8);
        p[0] = o0;
        p[1] = o1;
    }
}

// ---- fallback (proven R2 kernel) for shapes the fast path can't take ----
#define BM 64
#define BN 64
#define FBK 32
#define LDSW 68

__global__ __launch_bounds__(256) void mam_fallback(
    const float* __restrict__ A, const float* __restrict__ W,
    const float* __restrict__ bias, float* __restrict__ C,
    int M, int N, int K)
{
    __shared__ float Asf[FBK][LDSW];
    __shared__ float Wsf[FBK][LDSW];

    const int t  = threadIdx.x;
    const int tx = t & 15;
    const int ty = t >> 4;
    const int m0 = blockIdx.y * BM;
    const int n0 = blockIdx.x * BN;
    const int r  = t >> 3;
    const int kq = t & 7;

    const float* Aptr = A + (size_t)(m0 + r) * K + kq * 4;
    const float* Wptr = W + (size_t)(n0 + r) * K + kq * 4;

    float vmax[4][4], vmin[4][4];
#pragma unroll
    for (int i = 0; i < 4; ++i)
#pragma unroll
        for (int j = 0; j < 4; ++j) {
            vmax[i][j] = -INFINITY;
            vmin[i][j] =  INFINITY;
        }

    for (int k0 = 0; k0 < K; k0 += FBK) {
        float4 a0 = *(const float4*)(Aptr);
        float4 a1 = *(const float4*)(Aptr + (size_t)32 * K);
        float4 w0 = *(const float4*)(Wptr);
        float4 w1 = *(const float4*)(Wptr + (size_t)32 * K);
        Aptr += FBK;
        Wptr += FBK;

        const int kk = kq * 4;
        Asf[kk + 0][r]      = a0.x;
        Asf[kk + 1][r]      = a0.y;
        Asf[kk + 2][r]      = a0.z;
        Asf[kk + 3][r]      = a0.w;
        Asf[kk + 0][r + 32] = a1.x;
        Asf[kk + 1][r + 32] = a1.y;
        Asf[kk + 2][r + 32] = a1.z;
        Asf[kk + 3][r + 32] = a1.w;

        Wsf[kk + 0][r]      = w0.x;
        Wsf[kk + 1][r]      = w0.y;
        Wsf[kk + 2][r]      = w0.z;
        Wsf[kk + 3][r]      = w0.w;
        Wsf[kk + 0][r + 32] = w1.x;
        Wsf[kk + 1][r + 32] = w1.y;
        Wsf[kk + 2][r + 32] = w1.z;
        Wsf[kk + 3][r + 32] = w1.w;

        __syncthreads();

#pragma unroll
        for (int k = 0; k < FBK; k += 2) {
            float4 ta0 = *(const float4*)&Asf[k    ][ty * 4];
            float4 ta1 = *(const float4*)&Asf[k + 1][ty * 4];
            float4 tb0 = *(const float4*)&Wsf[k    ][tx * 4];
            float4 tb1 = *(const float4*)&Wsf[k + 1][tx * 4];

            float a0v[4] = {ta0.x, ta0.y, ta0.z, ta0.w};
            float a1v[4] = {ta1.x, ta1.y, ta1.z, ta1.w};
            float b0v[4] = {tb0.x, tb0.y, tb0.z, tb0.w};
            float b1v[4] = {tb1.x, tb1.y, tb1.z, tb1.w};

#pragma unroll
            for (int i = 0; i < 4; ++i)
#pragma unroll
                for (int j = 0; j < 4; ++j) {
                    float p0 = a0v[i] * b0v[j];
                    float p1 = a1v[i] * b1v[j];
                    mam_upd(vmax[i][j], vmin[i][j], p0, p1);
                }
        }
        __syncthreads();
    }

    float4 bv = *(const float4*)(bias + n0 + tx * 4);
#pragma unroll
    for (int i = 0; i < 4; ++i) {
        float4 o;
        o.x = vmax[i][0] + vmin[i][0] + bv.x;
        o.y = vmax[i][1] + vmin[i][1] + bv.y;
        o.z = vmax[i][2] + vmin[i][2] + bv.z;
        o.w = vmax[i][3] + vmin[i][3] + bv.w;
        *(float4*)(C + (size_t)(m0 + ty * 4 + i) * N + n0 + tx * 4) = o;
    }
}

extern "C" void kernel_launch(void* const* d_in, const int* in_sizes, int n_in,
                              void* d_out, int out_size, void* d_ws, size_t ws_size,
                              hipStream_t stream) {
    const float* x    = (const float*)d_in[0];
    const float* w    = (const float*)d_in[1];
    const float* bias = (const float*)d_in[2];
    float* out = (float*)d_out;

    const int N = in_sizes[2];
    const int K = in_sizes[1] / N;
    const int M = in_sizes[0] / K;

    const bool fast_ok = (K % (4 * BK) == 0) && (M % TS == 0) && (N % TS == 0);

    if (fast_ok) {
        dim3 grid(N / TS, M / TS);   // (16, 32) = 512 blocks
        mam_sk<<<grid, 256, 0, stream>>>(x, w, bias, out, M, N, K);
    } else {
        dim3 grid(N / BN, M / BM);
        mam_fallback<<<grid, 256, 0, stream>>>(x, w, bias, out, M, N, K);
    }
}

// Round 13
// 151.797 us; speedup vs baseline: 5.5782x; 1.0141x over previous
//
#include <hip/hip_runtime.h>
#include <math.h>

// MAM dense: C[m,n] = max_k(A[m,k]*W[n,k]) + min_k(A[m,k]*W[n,k]) + bias[n]
// A: [M,K] fp32, W: [N,K] fp32 (torch layout), C: [M,N]
//
// R13 = R12 + the AGPR fix. R12 counters: VGPR_Count=120 but 128 live
// accumulators and zero scratch traffic -> compiler homed accumulators in
// AGPRs (unified file, 120 arch + 128 accum = 248), paying
// v_accvgpr_read/write around every max3/min3 asm = measured 2.1x VALU
// instruction inflation (69k inst/wave vs 33k ideal). Fix:
// amdgpu_waves_per_eu(2,2) pins codegen at 2 waves/EU -> 256 arch-VGPR
// budget, demand ~210 fits entirely in arch VGPRs; tied "+v" operands
// remove residual copies. Grid is 512 blocks = 2 waves/SIMD (grid-bound
// occupancy; the R12 LDS union stays for 34.8 KB).

#define TS 64
#define BK 16
#define LDSP 68
#define STRIPF (BK * LDSP)   // 1088 floats per strip

__device__ __forceinline__ void mam_upd(float& mx, float& mn, float p0, float p1) {
    asm("v_max3_f32 %0, %1, %2, %0" : "+v"(mx) : "v"(p0), "v"(p1));
    asm("v_min3_f32 %0, %1, %2, %0" : "+v"(mn) : "v"(p0), "v"(p1));
}

__global__
__attribute__((amdgpu_flat_work_group_size(256, 256)))
__attribute__((amdgpu_waves_per_eu(2, 2)))
void mam_sk(
    const float* __restrict__ A, const float* __restrict__ W,
    const float* __restrict__ bias, float* __restrict__ C,
    int M, int N, int K)
{
    // union: [0..4*STRIPF) sA strips, [4*STRIPF..8*STRIPF) sW strips;
    // after the main loop (barrier) the same memory holds cmx/cmn (64x64 each).
    __shared__ __align__(16) float smem[8 * STRIPF];   // 34816 B
    float* cmx = smem;
    float* cmn = smem + TS * TS;

    const int t    = threadIdx.x;
    const int w    = t >> 6;        // wave id == k-group
    const int lane = t & 63;
    const int ty   = lane >> 3;     // m micro thread (8 rows)
    const int tx   = lane & 7;      // n micro thread (8 cols)
    const int m0   = blockIdx.y * TS;
    const int n0   = blockIdx.x * TS;
    const int kc   = K >> 2;        // 256 k per wave
    const int kb0  = w * kc;

    const int sr = lane >> 2;       // staging row 0..15
    const int sc = lane & 3;        // staging k-quad 0..3

    float* sAw = smem + (size_t)w * STRIPF;          // this wave's A strip
    float* sWw = smem + (size_t)(4 + w) * STRIPF;    // this wave's W strip

    const float* Ap = A + (size_t)(m0 + sr) * K + kb0 + sc * 4;
    const float* Wp = W + (size_t)(n0 + sr) * K + kb0 + sc * 4;

    float mx[8][8], mn[8][8];
#pragma unroll
    for (int i = 0; i < 8; ++i)
#pragma unroll
        for (int j = 0; j < 8; ++j) {
            mx[i][j] = -INFINITY;
            mn[i][j] =  INFINITY;
        }

    float4 ra[4], rw[4];
#pragma unroll
    for (int q = 0; q < 4; ++q) {
        ra[q] = *(const float4*)(Ap + (size_t)q * 16 * K);
        rw[q] = *(const float4*)(Wp + (size_t)q * 16 * K);
    }
    Ap += BK;
    Wp += BK;

    const int nStages = kc / BK;    // 16
    for (int s = 0; s < nStages; ++s) {
        // scatter current stage into this wave's strip (no barrier: strip is
        // wave-private; same-wave DS ops are ordered)
#pragma unroll
        for (int q = 0; q < 4; ++q) {
            const int mI = sr + q * 16;
            sAw[(sc * 4 + 0) * LDSP + mI] = ra[q].x;
            sAw[(sc * 4 + 1) * LDSP + mI] = ra[q].y;
            sAw[(sc * 4 + 2) * LDSP + mI] = ra[q].z;
            sAw[(sc * 4 + 3) * LDSP + mI] = ra[q].w;
            sWw[(sc * 4 + 0) * LDSP + mI] = rw[q].x;
            sWw[(sc * 4 + 1) * LDSP + mI] = rw[q].y;
            sWw[(sc * 4 + 2) * LDSP + mI] = rw[q].z;
            sWw[(sc * 4 + 3) * LDSP + mI] = rw[q].w;
        }
        // prefetch next stage while computing this one
        if (s + 1 < nStages) {
#pragma unroll
            for (int q = 0; q < 4; ++q) {
                ra[q] = *(const float4*)(Ap + (size_t)q * 16 * K);
                rw[q] = *(const float4*)(Wp + (size_t)q * 16 * K);
            }
            Ap += BK;
            Wp += BK;
        }

#pragma unroll
        for (int k = 0; k < BK; k += 2) {
            float4 a00 = *(const float4*)&sAw[(k    ) * LDSP + ty * 8];
            float4 a01 = *(const float4*)&sAw[(k    ) * LDSP + ty * 8 + 4];
            float4 a10 = *(const float4*)&sAw[(k + 1) * LDSP + ty * 8];
            float4 a11 = *(const float4*)&sAw[(k + 1) * LDSP + ty * 8 + 4];
            float4 w00 = *(const float4*)&sWw[(k    ) * LDSP + tx * 8];
            float4 w01 = *(const float4*)&sWw[(k    ) * LDSP + tx * 8 + 4];
            float4 w10 = *(const float4*)&sWw[(k + 1) * LDSP + tx * 8];
            float4 w11 = *(const float4*)&sWw[(k + 1) * LDSP + tx * 8 + 4];

            float a0[8] = {a00.x, a00.y, a00.z, a00.w, a01.x, a01.y, a01.z, a01.w};
            float a1[8] = {a10.x, a10.y, a10.z, a10.w, a11.x, a11.y, a11.z, a11.w};
            float b0[8] = {w00.x, w00.y, w00.z, w00.w, w01.x, w01.y, w01.z, w01.w};
            float b1[8] = {w10.x, w10.y, w10.z, w10.w, w11.x, w11.y, w11.z, w11.w};

#pragma unroll
            for (int i = 0; i < 8; ++i)
#pragma unroll
                for (int j = 0; j < 8; ++j) {
                    float p0 = a0[i] * b0[j];
                    float p1 = a1[i] * b1[j];
                    mam_upd(mx[i][j], mn[i][j], p0, p1);
                }
        }
    }

    // strips now dead; cmx/cmn overlap them -> drain all waves first
    __syncthreads();

    // ---- cross-wave combine: sequential merge rounds through LDS ----
    for (int rnd = 0; rnd < 4; ++rnd) {
        if (w == rnd) {
#pragma unroll
            for (int i = 0; i < 8; ++i)
#pragma unroll
                for (int j = 0; j < 8; ++j) {
                    const int idx = (ty * 8 + i) * TS + tx * 8 + j;
                    if (rnd == 0) {
                        cmx[idx] = mx[i][j];
                        cmn[idx] = mn[i][j];
                    } else {
                        cmx[idx] = fmaxf(cmx[idx], mx[i][j]);
                        cmn[idx] = fminf(cmn[idx], mn[i][j]);
                    }
                }
        }
        __syncthreads();
    }

    // ---- bias + store: wave w writes micro-rows i = {2w, 2w+1} ----
    float4 blo = *(const float4*)(bias + n0 + tx * 8);
    float4 bhi = *(const float4*)(bias + n0 + tx * 8 + 4);
#pragma unroll
    for (int i2 = 0; i2 < 2; ++i2) {
        const int i   = w * 2 + i2;
        const int row = ty * 8 + i;
        const int idx = row * TS + tx * 8;
        float4 o0, o1;
        o0.x = cmx[idx + 0] + cmn[idx + 0] + blo.x;
        o0.y = cmx[idx + 1] + cmn[idx + 1] + blo.y;
        o0.z = cmx[idx + 2] + cmn[idx + 2] + blo.z;
        o0.w = cmx[idx + 3] + cmn[idx + 3] + blo.w;
        o1.x = cmx[idx + 4] + cmn[idx + 4] + bhi.x;
        o1.y = cmx[idx + 5] + cmn[idx + 5] + bhi.y;
        o1.z = cmx[idx + 6] + cmn[idx + 6] + bhi.z;
        o1.w = cmx[idx + 7] + cmn[idx + 7] + bhi.w;
        float4* p = (float4*)(C + (size_t)(m0 + row) * N + n0 + tx * 8);
        p[0] = o0;
        p[1] = o1;
    }
}

// ---- fallback (proven R2 kernel) for shapes the fast path can't take ----
#define BM 64
#define BN 64
#define FBK 32
#define LDSW 68

__device__ __forceinline__ void mam_upd_fb(float& mx, float& mn, float p0, float p1) {
    float nmx, nmn;
    asm("v_max3_f32 %0, %1, %2, %3" : "=v"(nmx) : "v"(p0), "v"(p1), "v"(mx));
    asm("v_min3_f32 %0, %1, %2, %3" : "=v"(nmn) : "v"(p0), "v"(p1), "v"(mn));
    mx = nmx;
    mn = nmn;
}

__global__ __launch_bounds__(256) void mam_fallback(
    const float* __restrict__ A, const float* __restrict__ W,
    const float* __restrict__ bias, float* __restrict__ C,
    int M, int N, int K)
{
    __shared__ float Asf[FBK][LDSW];
    __shared__ float Wsf[FBK][LDSW];

    const int t  = threadIdx.x;
    const int tx = t & 15;
    const int ty = t >> 4;
    const int m0 = blockIdx.y * BM;
    const int n0 = blockIdx.x * BN;
    const int r  = t >> 3;
    const int kq = t & 7;

    const float* Aptr = A + (size_t)(m0 + r) * K + kq * 4;
    const float* Wptr = W + (size_t)(n0 + r) * K + kq * 4;

    float vmax[4][4], vmin[4][4];
#pragma unroll
    for (int i = 0; i < 4; ++i)
#pragma unroll
        for (int j = 0; j < 4; ++j) {
            vmax[i][j] = -INFINITY;
            vmin[i][j] =  INFINITY;
        }

    for (int k0 = 0; k0 < K; k0 += FBK) {
        float4 a0 = *(const float4*)(Aptr);
        float4 a1 = *(const float4*)(Aptr + (size_t)32 * K);
        float4 w0 = *(const float4*)(Wptr);
        float4 w1 = *(const float4*)(Wptr + (size_t)32 * K);
        Aptr += FBK;
        Wptr += FBK;

        const int kk = kq * 4;
        Asf[kk + 0][r]      = a0.x;
        Asf[kk + 1][r]      = a0.y;
        Asf[kk + 2][r]      = a0.z;
        Asf[kk + 3][r]      = a0.w;
        Asf[kk + 0][r + 32] = a1.x;
        Asf[kk + 1][r + 32] = a1.y;
        Asf[kk + 2][r + 32] = a1.z;
        Asf[kk + 3][r + 32] = a1.w;

        Wsf[kk + 0][r]      = w0.x;
        Wsf[kk + 1][r]      = w0.y;
        Wsf[kk + 2][r]      = w0.z;
        Wsf[kk + 3][r]      = w0.w;
        Wsf[kk + 0][r + 32] = w1.x;
        Wsf[kk + 1][r + 32] = w1.y;
        Wsf[kk + 2][r + 32] = w1.z;
        Wsf[kk + 3][r + 32] = w1.w;

        __syncthreads();

#pragma unroll
        for (int k = 0; k < FBK; k += 2) {
            float4 ta0 = *(const float4*)&Asf[k    ][ty * 4];
            float4 ta1 = *(const float4*)&Asf[k + 1][ty * 4];
            float4 tb0 = *(const float4*)&Wsf[k    ][tx * 4];
            float4 tb1 = *(const float4*)&Wsf[k + 1][tx * 4];

            float a0v[4] = {ta0.x, ta0.y, ta0.z, ta0.w};
            float a1v[4] = {ta1.x, ta1.y, ta1.z, ta1.w};
            float b0v[4] = {tb0.x, tb0.y, tb0.z, tb0.w};
            float b1v[4] = {tb1.x, tb1.y, tb1.z, tb1.w};

#pragma unroll
            for (int i = 0; i < 4; ++i)
#pragma unroll
                for (int j = 0; j < 4; ++j) {
                    float p0 = a0v[i] * b0v[j];
                    float p1 = a1v[i] * b1v[j];
                    mam_upd_fb(vmax[i][j], vmin[i][j], p0, p1);
                }
        }
        __syncthreads();
    }

    float4 bv = *(const float4*)(bias + n0 + tx * 4);
#pragma unroll
    for (int i = 0; i < 4; ++i) {
        float4 o;
        o.x = vmax[i][0] + vmin[i][0] + bv.x;
        o.y = vmax[i][1] + vmin[i][1] + bv.y;
        o.z = vmax[i][2] + vmin[i][2] + bv.z;
        o.w = vmax[i][3] + vmin[i][3] + bv.w;
        *(float4*)(C + (size_t)(m0 + ty * 4 + i) * N + n0 + tx * 4) = o;
    }
}

extern "C" void kernel_launch(void* const* d_in, const int* in_sizes, int n_in,
                              void* d_out, int out_size, void* d_ws, size_t ws_size,
                              hipStream_t stream) {
    const float* x    = (const float*)d_in[0];
    const float* w    = (const float*)d_in[1];
    const float* bias = (const float*)d_in[2];
    float* out = (float*)d_out;

    const int N = in_sizes[2];
    const int K = in_sizes[1] / N;
    const int M = in_sizes[0] / K;

    const bool fast_ok = (K % (4 * BK) == 0) && (M % TS == 0) && (N % TS == 0);

    if (fast_ok) {
        dim3 grid(N / TS, M / TS);   // (16, 32) = 512 blocks
        mam_sk<<<grid, 256, 0, stream>>>(x, w, bias, out, M, N, K);
    } else {
        dim3 grid(N / BN, M / BM);
        mam_fallback<<<grid, 256, 0, stream>>>(x, w, bias, out, M, N, K);
    }
}